// Round 2
// baseline (186.148 us; speedup 1.0000x reference)
//
#include <hip/hip_runtime.h>
#include <hip/hip_bf16.h>

#define N0C 100000
#define N1C 50000
#define N2C 25000

typedef _Float16 f16;
typedef _Float16 f16x2 __attribute__((ext_vector_type(2)));
typedef _Float16 f16x4 __attribute__((ext_vector_type(4)));
typedef _Float16 f16x8 __attribute__((ext_vector_type(8)));
typedef float f32x4 __attribute__((ext_vector_type(4)));

// ---------------------------------------------------------------- prep ------
// ws1t[n][k] = f16(Ws1[k][n])   (256x256)
// ws2t[n][k] = f16(Ws2[k][n])   (128x256)
// wd1e[k][h] = sum_c Wd1[k][h*128+c] * ad1[h][c]
// wd2e[k]    = sum_c Wd2[k][c] * ad2[c]
// bns[c] = g1[c]*rsqrt(v1[c]+1e-5); bnt[c] = (b1[c]-m1[c])*bns[c] + beta1[c]
__global__ void prep_kernel(const float* __restrict__ Ws1, const float* __restrict__ Wd1,
                            const float* __restrict__ ad1,
                            const float* __restrict__ Ws2, const float* __restrict__ Wd2,
                            const float* __restrict__ ad2,
                            const float* __restrict__ b1, const float* __restrict__ g1,
                            const float* __restrict__ beta1, const float* __restrict__ m1,
                            const float* __restrict__ v1,
                            f16* __restrict__ ws1t, f16* __restrict__ ws2t,
                            float* __restrict__ wd1e, float* __restrict__ wd2e,
                            float* __restrict__ bns, float* __restrict__ bnt) {
    int idx = blockIdx.x * 256 + threadIdx.x;
    if (idx < 65536) {
        int n = idx >> 8, k = idx & 255;
        ws1t[n * 256 + k] = (f16)Ws1[k * 256 + n];
    } else if (idx < 98304) {
        int r = idx - 65536;
        int n = r >> 8, k = r & 255;
        ws2t[n * 256 + k] = (f16)Ws2[k * 128 + n];
    } else if (idx < 98816) {
        int r = idx - 98304;
        int k = r >> 1, h = r & 1;
        float s = 0.f;
        for (int c = 0; c < 128; c++) s += Wd1[k * 256 + h * 128 + c] * ad1[h * 128 + c];
        wd1e[k * 2 + h] = s;
    } else if (idx < 99072) {
        int k = idx - 98816;
        float s = 0.f;
        for (int c = 0; c < 128; c++) s += Wd2[k * 128 + c] * ad2[c];
        wd2e[k] = s;
    } else if (idx < 99328) {
        int c = idx - 99072;
        float s = g1[c] * rsqrtf(v1[c] + 1e-5f);
        bns[c] = s;
        bnt[c] = (b1[c] - m1[c]) * s + beta1[c];
    }
}

// ---------------------------------------------------------------- gemm1 -----
// hs = f16(x) @ Ws1  -> [N0, 256] f16, plus a_s1[N0][2], a_d1[N1][2]
// block: 64 rows x 256 cols, 4 waves (each wave 16 rows x full 256 cols), K=256
// LDS: A tile [64][256] f16 (32KB) + B chunk [64][256] f16 (32KB), XOR-swizzled
__global__ __launch_bounds__(256, 2) void gemm1_kernel(
    const float* __restrict__ x, const f16* __restrict__ wt,
    const float* __restrict__ wde, const float* __restrict__ asv,
    f16* __restrict__ hs, float* __restrict__ as_out, float* __restrict__ ad_out) {
    __shared__ __align__(16) unsigned char smem[65536];
    unsigned char* smA = smem;
    unsigned char* smB = smem + 32768;
    const int t = threadIdx.x;
    const int wave = t >> 6, lane = t & 63;
    const int rowb = blockIdx.x * 64;

    // stage A (f32 -> f16), whole K
    {
        int rl = t >> 2, q = t & 3;
        int grow = rowb + rl;
        const float4* xr = (const float4*)(x + (size_t)grow * 256);
        int sw = (rl & 7) << 4;
#pragma unroll
        for (int i = 0; i < 16; i++) {
            int c4 = q + i * 4;  // float4 index 0..63
            float4 v;
            if (grow < N0C) v = xr[c4];
            else v = make_float4(0.f, 0.f, 0.f, 0.f);
            f16x4 hv = {(f16)v.x, (f16)v.y, (f16)v.z, (f16)v.w};
            *(f16x4*)(smA + rl * 512 + ((c4 * 8) ^ sw)) = hv;
        }
    }

    f32x4 acc[16] = {};
    float pd0 = 0.f, pd1 = 0.f;

#pragma unroll
    for (int ch = 0; ch < 4; ch++) {
        __syncthreads();
        {   // stage B chunk: rows n = ch*64 + nl from wt[n][k]
            int nl = t >> 2, q = t & 3;
            const unsigned char* src = (const unsigned char*)(wt + (size_t)(ch * 64 + nl) * 256);
            int sw = (nl & 7) << 4;
#pragma unroll
            for (int i = 0; i < 8; i++) {
                int boff = q * 128 + i * 16;
                int4 v = *(const int4*)(src + boff);
                *(int4*)(smB + nl * 512 + (boff ^ sw)) = v;
            }
        }
        __syncthreads();
        int arow = wave * 16 + (lane & 15);
        int asw = (arow & 7) << 4;
#pragma unroll
        for (int s = 0; s < 8; s++) {
            int kb = s * 64 + (lane >> 4) * 16;  // byte offset in k
            f16x8 af = *(const f16x8*)(smA + arow * 512 + (kb ^ asw));
            if (ch == 0) {
                int kbase = s * 32 + (lane >> 4) * 8;
#pragma unroll
                for (int j = 0; j < 8; j++) {
                    float av = (float)af[j];
                    pd0 += av * wde[(kbase + j) * 2 + 0];
                    pd1 += av * wde[(kbase + j) * 2 + 1];
                }
            }
#pragma unroll
            for (int tt = 0; tt < 4; tt++) {
                int brow = tt * 16 + (lane & 15);
                f16x8 bf = *(const f16x8*)(smB + brow * 512 + (kb ^ ((brow & 7) << 4)));
                acc[ch * 4 + tt] = __builtin_amdgcn_mfma_f32_16x16x32_f16(af, bf, acc[ch * 4 + tt], 0, 0, 0);
            }
        }
    }

    const int rg = lane >> 4, lc = lane & 15;
    // a_s partials (from f32 accumulators, pre-rounding)
    float ps0[4] = {0, 0, 0, 0}, ps1[4] = {0, 0, 0, 0};
#pragma unroll
    for (int cg = 0; cg < 16; cg++) {
        int col = (cg >> 2) * 64 + (cg & 3) * 16 + lc;
        float a = asv[col];
        if (cg < 8) {
#pragma unroll
            for (int r = 0; r < 4; r++) ps0[r] += acc[cg][r] * a;
        } else {
#pragma unroll
            for (int r = 0; r < 4; r++) ps1[r] += acc[cg][r] * a;
        }
    }
#pragma unroll
    for (int d = 1; d < 16; d <<= 1) {
#pragma unroll
        for (int r = 0; r < 4; r++) {
            ps0[r] += __shfl_xor(ps0[r], d);
            ps1[r] += __shfl_xor(ps1[r], d);
        }
    }
    if (lc == 0) {
#pragma unroll
        for (int r = 0; r < 4; r++) {
            int grow = rowb + wave * 16 + rg * 4 + r;
            if (grow < N0C) {
                as_out[grow * 2 + 0] = ps0[r];
                as_out[grow * 2 + 1] = ps1[r];
            }
        }
    }
    // a_d reduce (k-partials live in lanes l, l+16, l+32, l+48 for row lane&15)
    pd0 += __shfl_xor(pd0, 16); pd0 += __shfl_xor(pd0, 32);
    pd1 += __shfl_xor(pd1, 16); pd1 += __shfl_xor(pd1, 32);
    if (lane < 16) {
        int grow = rowb + wave * 16 + lane;
        if (grow < N1C) {
            ad_out[grow * 2 + 0] = pd0;
            ad_out[grow * 2 + 1] = pd1;
        }
    }
    // store hs
#pragma unroll
    for (int cg = 0; cg < 16; cg++) {
        int col = (cg >> 2) * 64 + (cg & 3) * 16 + lc;
#pragma unroll
        for (int r = 0; r < 4; r++) {
            int grow = rowb + wave * 16 + rg * 4 + r;
            if (grow < N0C) hs[(size_t)grow * 256 + col] = (f16)acc[cg][r];
        }
    }
}

// ---------------------------------------------------------------- gemm2 -----
// hs2 = h @ Ws2 -> [N1, 128] f16, plus a_s2[N1], a_d2[N2]
__global__ __launch_bounds__(256, 2) void gemm2_kernel(
    const f16* __restrict__ h, const f16* __restrict__ wt,
    const float* __restrict__ wde, const float* __restrict__ asv,
    f16* __restrict__ hs2, float* __restrict__ as_out, float* __restrict__ ad_out) {
    __shared__ __align__(16) unsigned char smem[65536];
    unsigned char* smA = smem;
    unsigned char* smB = smem + 32768;
    const int t = threadIdx.x;
    const int wave = t >> 6, lane = t & 63;
    const int rowb = blockIdx.x * 64;

    {   // stage A (f16 direct)
        int rl = t >> 2, q = t & 3;
        int grow = rowb + rl;
        const unsigned char* src = (const unsigned char*)(h + (size_t)grow * 256);
        int sw = (rl & 7) << 4;
#pragma unroll
        for (int i = 0; i < 8; i++) {
            int boff = q * 128 + i * 16;
            int4 v;
            if (grow < N1C) v = *(const int4*)(src + boff);
            else v = make_int4(0, 0, 0, 0);
            *(int4*)(smA + rl * 512 + (boff ^ sw)) = v;
        }
    }

    f32x4 acc[8] = {};
    float pd = 0.f;

#pragma unroll
    for (int ch = 0; ch < 2; ch++) {
        __syncthreads();
        {
            int nl = t >> 2, q = t & 3;
            const unsigned char* src = (const unsigned char*)(wt + (size_t)(ch * 64 + nl) * 256);
            int sw = (nl & 7) << 4;
#pragma unroll
            for (int i = 0; i < 8; i++) {
                int boff = q * 128 + i * 16;
                int4 v = *(const int4*)(src + boff);
                *(int4*)(smB + nl * 512 + (boff ^ sw)) = v;
            }
        }
        __syncthreads();
        int arow = wave * 16 + (lane & 15);
        int asw = (arow & 7) << 4;
#pragma unroll
        for (int s = 0; s < 8; s++) {
            int kb = s * 64 + (lane >> 4) * 16;
            f16x8 af = *(const f16x8*)(smA + arow * 512 + (kb ^ asw));
            if (ch == 0) {
                int kbase = s * 32 + (lane >> 4) * 8;
#pragma unroll
                for (int j = 0; j < 8; j++) pd += (float)af[j] * wde[kbase + j];
            }
#pragma unroll
            for (int tt = 0; tt < 4; tt++) {
                int brow = tt * 16 + (lane & 15);
                f16x8 bf = *(const f16x8*)(smB + brow * 512 + (kb ^ ((brow & 7) << 4)));
                acc[ch * 4 + tt] = __builtin_amdgcn_mfma_f32_16x16x32_f16(af, bf, acc[ch * 4 + tt], 0, 0, 0);
            }
        }
    }

    const int rg = lane >> 4, lc = lane & 15;
    float ps[4] = {0, 0, 0, 0};
#pragma unroll
    for (int cg = 0; cg < 8; cg++) {
        int col = (cg >> 2) * 64 + (cg & 3) * 16 + lc;
        float a = asv[col];
#pragma unroll
        for (int r = 0; r < 4; r++) ps[r] += acc[cg][r] * a;
    }
#pragma unroll
    for (int d = 1; d < 16; d <<= 1) {
#pragma unroll
        for (int r = 0; r < 4; r++) ps[r] += __shfl_xor(ps[r], d);
    }
    if (lc == 0) {
#pragma unroll
        for (int r = 0; r < 4; r++) {
            int grow = rowb + wave * 16 + rg * 4 + r;
            if (grow < N1C) as_out[grow] = ps[r];
        }
    }
    pd += __shfl_xor(pd, 16); pd += __shfl_xor(pd, 32);
    if (lane < 16) {
        int grow = rowb + wave * 16 + lane;
        if (grow < N2C) ad_out[grow] = pd;
    }
#pragma unroll
    for (int cg = 0; cg < 8; cg++) {
        int col = (cg >> 2) * 64 + (cg & 3) * 16 + lc;
#pragma unroll
        for (int r = 0; r < 4; r++) {
            int grow = rowb + wave * 16 + rg * 4 + r;
            if (grow < N1C) hs2[(size_t)grow * 128 + col] = (f16)acc[cg][r];
        }
    }
}

// ---------------------------------------------------------------- agg1 ------
// one wave per dst node: masked edge softmax (heads=2) + gather-accumulate
// + fused bias/BN/leaky_relu(0.01), writes h [N1,256] f16
__global__ void agg1_kernel(const int* __restrict__ col1, const int* __restrict__ t1,
                            const int* __restrict__ timep, const int* __restrict__ intervalp,
                            const float* __restrict__ a_s, const float* __restrict__ a_d,
                            const f16* __restrict__ hs,
                            const float* __restrict__ bns, const float* __restrict__ bnt,
                            f16* __restrict__ h) {
    int wid = (blockIdx.x * blockDim.x + threadIdx.x) >> 6;
    if (wid >= N1C) return;
    int lane = threadIdx.x & 63;
    int T = timep[0], I = intervalp[0];
    int j = lane & 15;
    int c = col1[wid * 16 + j];
    int tv = t1[wid * 16 + j];
    bool mk = (tv >= T) && (tv < T + I);
    float e0 = -INFINITY, e1 = -INFINITY;
    if (mk) {
        float s0 = a_s[c * 2 + 0] + a_d[wid * 2 + 0];
        float s1 = a_s[c * 2 + 1] + a_d[wid * 2 + 1];
        e0 = s0 > 0.f ? s0 : 0.2f * s0;
        e1 = s1 > 0.f ? s1 : 0.2f * s1;
    }
    float m0 = e0, m1 = e1;
#pragma unroll
    for (int d = 1; d < 16; d <<= 1) {
        m0 = fmaxf(m0, __shfl_xor(m0, d));
        m1 = fmaxf(m1, __shfl_xor(m1, d));
    }
    float ex0 = mk ? __expf(e0 - m0) : 0.f;
    float ex1 = mk ? __expf(e1 - m1) : 0.f;
    float s0 = ex0, s1 = ex1;
#pragma unroll
    for (int d = 1; d < 16; d <<= 1) {
        s0 += __shfl_xor(s0, d);
        s1 += __shfl_xor(s1, d);
    }
    float r0 = 1.f / fmaxf(s0, 1e-16f);
    float r1 = 1.f / fmaxf(s1, 1e-16f);
    unsigned long long mb = __ballot(mk) & 0xFFFFull;
    int head = lane >> 5;
    float rden = head ? r1 : r0;
    float acc0 = 0.f, acc1 = 0.f, acc2 = 0.f, acc3 = 0.f;
    while (mb) {
        int jj = __builtin_ctzll(mb);
        mb &= mb - 1;
        int cj = __shfl(c, jj);
        float w0 = __shfl(ex0, jj), w1 = __shfl(ex1, jj);
        float w = (head ? w1 : w0) * rden;
        f16x4 v = *(const f16x4*)(hs + (size_t)cj * 256 + lane * 4);
        acc0 += w * (float)v[0];
        acc1 += w * (float)v[1];
        acc2 += w * (float)v[2];
        acc3 += w * (float)v[3];
    }
    int cb = lane * 4;
    float4 sc = *(const float4*)(bns + cb);
    float4 sh = *(const float4*)(bnt + cb);
    float o0 = acc0 * sc.x + sh.x; o0 = o0 > 0.f ? o0 : 0.01f * o0;
    float o1 = acc1 * sc.y + sh.y; o1 = o1 > 0.f ? o1 : 0.01f * o1;
    float o2 = acc2 * sc.z + sh.z; o2 = o2 > 0.f ? o2 : 0.01f * o2;
    float o3 = acc3 * sc.w + sh.w; o3 = o3 > 0.f ? o3 : 0.01f * o3;
    f16x4 ov = {(f16)o0, (f16)o1, (f16)o2, (f16)o3};
    *(f16x4*)(h + (size_t)wid * 256 + cb) = ov;
}

// ---------------------------------------------------------------- agg2 ------
// one wave per dst: masked softmax (1 head), gather [N1,128] f16, + b2, f32 out
__global__ void agg2_kernel(const int* __restrict__ col2, const int* __restrict__ t2,
                            const int* __restrict__ timep, const int* __restrict__ intervalp,
                            const float* __restrict__ a_s, const float* __restrict__ a_d,
                            const f16* __restrict__ hs2,
                            const float* __restrict__ b2, float* __restrict__ out) {
    int wid = (blockIdx.x * blockDim.x + threadIdx.x) >> 6;
    if (wid >= N2C) return;
    int lane = threadIdx.x & 63;
    int T = timep[0], I = intervalp[0];
    int j = lane & 15;
    int c = col2[wid * 16 + j];
    int tv = t2[wid * 16 + j];
    bool mk = (tv >= T) && (tv < T + I);
    float e = -INFINITY;
    if (mk) {
        float s = a_s[c] + a_d[wid];
        e = s > 0.f ? s : 0.2f * s;
    }
    float m = e;
#pragma unroll
    for (int d = 1; d < 16; d <<= 1) m = fmaxf(m, __shfl_xor(m, d));
    float ex = mk ? __expf(e - m) : 0.f;
    float s = ex;
#pragma unroll
    for (int d = 1; d < 16; d <<= 1) s += __shfl_xor(s, d);
    float r = 1.f / fmaxf(s, 1e-16f);
    unsigned long long mb = __ballot(mk) & 0xFFFFull;
    float acc0 = 0.f, acc1 = 0.f;
    while (mb) {
        int jj = __builtin_ctzll(mb);
        mb &= mb - 1;
        int cj = __shfl(c, jj);
        float w = __shfl(ex, jj) * r;
        f16x2 v = *(const f16x2*)(hs2 + (size_t)cj * 128 + lane * 2);
        acc0 += w * (float)v[0];
        acc1 += w * (float)v[1];
    }
    float2 o = make_float2(acc0 + b2[lane * 2], acc1 + b2[lane * 2 + 1]);
    *(float2*)(out + (size_t)wid * 128 + lane * 2) = o;
}

// ---------------------------------------------------------------- launch ----
extern "C" void kernel_launch(void* const* d_in, const int* in_sizes, int n_in,
                              void* d_out, int out_size, void* d_ws, size_t ws_size,
                              hipStream_t stream) {
    const float* x = (const float*)d_in[0];
    const int* col1 = (const int*)d_in[2];
    const int* t1 = (const int*)d_in[3];
    const int* col2 = (const int*)d_in[5];
    const int* t2 = (const int*)d_in[6];
    const int* timep = (const int*)d_in[7];
    const int* intervalp = (const int*)d_in[8];
    const float* Ws1 = (const float*)d_in[9];
    const float* Wd1 = (const float*)d_in[10];
    const float* as1 = (const float*)d_in[11];
    const float* ad1 = (const float*)d_in[12];
    const float* b1 = (const float*)d_in[13];
    const float* g1 = (const float*)d_in[14];
    const float* beta1 = (const float*)d_in[15];
    const float* m1 = (const float*)d_in[16];
    const float* v1 = (const float*)d_in[17];
    const float* Ws2 = (const float*)d_in[18];
    const float* Wd2 = (const float*)d_in[19];
    const float* as2 = (const float*)d_in[20];
    const float* ad2 = (const float*)d_in[21];
    const float* b2 = (const float*)d_in[22];
    float* out = (float*)d_out;

    char* ws = (char*)d_ws;
    size_t off = 0;
    auto alloc = [&](size_t bytes) {
        size_t o = off;
        off += (bytes + 511) & ~(size_t)511;
        return o;
    };
    f16* hs = (f16*)(ws + alloc((size_t)N0C * 256 * 2));
    f16* h = (f16*)(ws + alloc((size_t)N1C * 256 * 2));
    f16* hs2 = (f16*)(ws + alloc((size_t)N1C * 128 * 2));
    float* a_s1 = (float*)(ws + alloc((size_t)N0C * 2 * 4));
    float* a_d1 = (float*)(ws + alloc((size_t)N1C * 2 * 4));
    float* a_s2 = (float*)(ws + alloc((size_t)N1C * 4));
    float* a_d2 = (float*)(ws + alloc((size_t)N2C * 4));
    f16* ws1t = (f16*)(ws + alloc((size_t)256 * 256 * 2));
    f16* ws2t = (f16*)(ws + alloc((size_t)128 * 256 * 2));
    float* wd1e = (float*)(ws + alloc(512 * 4));
    float* wd2e = (float*)(ws + alloc(256 * 4));
    float* bns = (float*)(ws + alloc(256 * 4));
    float* bnt = (float*)(ws + alloc(256 * 4));

    prep_kernel<<<388, 256, 0, stream>>>(Ws1, Wd1, ad1, Ws2, Wd2, ad2,
                                         b1, g1, beta1, m1, v1,
                                         ws1t, ws2t, wd1e, wd2e, bns, bnt);
    gemm1_kernel<<<(N0C + 63) / 64, 256, 0, stream>>>(x, ws1t, wd1e, as1, hs, a_s1, a_d1);
    agg1_kernel<<<N1C / 4, 256, 0, stream>>>(col1, t1, timep, intervalp,
                                             a_s1, a_d1, hs, bns, bnt, h);
    gemm2_kernel<<<(N1C + 63) / 64, 256, 0, stream>>>(h, ws2t, wd2e, as2, hs2, a_s2, a_d2);
    agg2_kernel<<<N2C / 4, 256, 0, stream>>>(col2, t2, timep, intervalp,
                                             a_s2, a_d2, hs2, b2, out);
}

// Round 3
// 153.083 us; speedup vs baseline: 1.2160x; 1.2160x over previous
//
#include <hip/hip_runtime.h>
#include <hip/hip_bf16.h>

#define N0C 100000
#define N1C 50000
#define N2C 25000

typedef _Float16 f16;
typedef _Float16 f16x2 __attribute__((ext_vector_type(2)));
typedef _Float16 f16x4 __attribute__((ext_vector_type(4)));
typedef _Float16 f16x8 __attribute__((ext_vector_type(8)));
typedef float f32x16 __attribute__((ext_vector_type(16)));

// ---------------------------------------------------------------- prep1 -----
// per-k folded attention vectors + BN constants
// e1[k][4] = {Ws1[:,0:128]@as1_h0, Ws1[:,128:]@as1_h1, Wd1[:,0:128]@ad1_h0, Wd1[:,128:]@ad1_h1}
// e2[k][2] = {Ws2@as2, Wd2@ad2}
__global__ void prep1_kernel(const float* __restrict__ Ws1, const float* __restrict__ Wd1,
                             const float* __restrict__ as1, const float* __restrict__ ad1,
                             const float* __restrict__ Ws2, const float* __restrict__ Wd2,
                             const float* __restrict__ as2, const float* __restrict__ ad2,
                             const float* __restrict__ b1, const float* __restrict__ g1,
                             const float* __restrict__ beta1, const float* __restrict__ m1,
                             const float* __restrict__ v1,
                             float* __restrict__ e1, float* __restrict__ e2,
                             float* __restrict__ bns, float* __restrict__ bnt) {
    int k = threadIdx.x;  // 256 threads, 1 block
    float s0 = 0.f, s1 = 0.f, d0 = 0.f, d1 = 0.f;
    for (int c = 0; c < 128; c++) {
        s0 += Ws1[k * 256 + c] * as1[c];
        s1 += Ws1[k * 256 + 128 + c] * as1[128 + c];
        d0 += Wd1[k * 256 + c] * ad1[c];
        d1 += Wd1[k * 256 + 128 + c] * ad1[128 + c];
    }
    e1[k * 4 + 0] = s0; e1[k * 4 + 1] = s1; e1[k * 4 + 2] = d0; e1[k * 4 + 3] = d1;
    float t0 = 0.f, t1 = 0.f;
    for (int c = 0; c < 128; c++) {
        t0 += Ws2[k * 128 + c] * as2[c];
        t1 += Wd2[k * 128 + c] * ad2[c];
    }
    e2[k * 2 + 0] = t0; e2[k * 2 + 1] = t1;
    float sc = g1[k] * rsqrtf(v1[k] + 1e-5f);
    bns[k] = sc;
    bnt[k] = (b1[k] - m1[k]) * sc + beta1[k];
}

// ---------------------------------------------------------------- prep2 -----
// fragment-linear B layouts for 32x32x16 MFMA:
// bfl1: [9 nt][16 kb][64 lane][8 j]  (nt 0-7: Ws1 cols; nt 8: e1 pad cols 0-3)
// bfl2: [5 nt][16 kb][64 lane][8 j]  (nt 0-3: Ws2 cols; nt 4: e2 pad cols 0-1)
// element (nt,kb,lane,j): n = nt*32 + (lane&31), k = kb*16 + (lane>>5)*8 + j
__global__ void prep2_kernel(const float* __restrict__ Ws1, const float* __restrict__ Ws2,
                             const float* __restrict__ e1, const float* __restrict__ e2,
                             f16* __restrict__ bfl1, f16* __restrict__ bfl2) {
    int i = blockIdx.x * 256 + threadIdx.x;
    if (i < 73728) {
        int j = i & 7, lane = (i >> 3) & 63, kb = (i >> 9) & 15, nt = i >> 13;
        int c = lane & 31, hi = lane >> 5;
        int k = kb * 16 + hi * 8 + j;
        float v;
        if (nt < 8) v = Ws1[k * 256 + nt * 32 + c];
        else v = (c < 4) ? e1[k * 4 + c] : 0.f;
        bfl1[i] = (f16)v;
    } else {
        int i2 = i - 73728;
        if (i2 < 40960) {
            int j = i2 & 7, lane = (i2 >> 3) & 63, kb = (i2 >> 9) & 15, nt = i2 >> 13;
            int c = lane & 31, hi = lane >> 5;
            int k = kb * 16 + hi * 8 + j;
            float v;
            if (nt < 4) v = Ws2[k * 128 + nt * 32 + c];
            else v = (c < 2) ? e2[k * 2 + c] : 0.f;
            bfl2[i2] = (f16)v;
        }
    }
}

// ---------------------------------------------------------------- gemm1 -----
// hs = f16(x) @ Ws1 -> [N0,256] f16, a_s1[N0][2], a_d1[N1][2] via pad tile.
// No LDS, no barriers. Block = 4 waves; wave owns 32 rows x 256 cols, K=256.
// A-frags: 16 x f16x8 (64 VGPR) from global. B-frags: coalesced dwordx4 from
// fragment-linear bfl1 (L2-resident). Two accumulator groups (nt 0-3, 4-8).
__global__ __launch_bounds__(256, 2) void gemm1_kernel(
    const float* __restrict__ x, const f16* __restrict__ bfl,
    f16* __restrict__ hs, float* __restrict__ as_out, float* __restrict__ ad_out) {
    const int lane = threadIdx.x & 63, wave = threadIdx.x >> 6;
    const int col = lane & 31, hi = lane >> 5;
    const int r0 = blockIdx.x * 128 + wave * 32;
    const int row = r0 + col;

    f16x8 af[16];
#pragma unroll
    for (int kb = 0; kb < 16; kb++) {
        float4 a0, a1;
        if (row < N0C) {
            const float4* p = (const float4*)(x + (size_t)row * 256 + kb * 16 + hi * 8);
            a0 = p[0]; a1 = p[1];
        } else {
            a0 = make_float4(0.f, 0.f, 0.f, 0.f);
            a1 = a0;
        }
        af[kb] = (f16x8){(f16)a0.x, (f16)a0.y, (f16)a0.z, (f16)a0.w,
                         (f16)a1.x, (f16)a1.y, (f16)a1.z, (f16)a1.w};
    }

    // ---- group 1: nt 0..3 ----
    {
        f32x16 acc[4] = {};
#pragma unroll
        for (int kb = 0; kb < 16; kb++) {
#pragma unroll
            for (int nt = 0; nt < 4; nt++) {
                f16x8 bf = *(const f16x8*)(bfl + ((size_t)(nt * 16 + kb) * 64 + lane) * 8);
                acc[nt] = __builtin_amdgcn_mfma_f32_32x32x16_f16(af[kb], bf, acc[nt], 0, 0, 0);
            }
        }
#pragma unroll
        for (int nt = 0; nt < 4; nt++)
#pragma unroll
            for (int r = 0; r < 16; r++) {
                int grow = r0 + (r & 3) + 8 * (r >> 2) + 4 * hi;
                if (grow < N0C) hs[(size_t)grow * 256 + nt * 32 + col] = (f16)acc[nt][r];
            }
    }
    // ---- group 2: nt 4..8 (8 = attention pad tile) ----
    {
        f32x16 acc[5] = {};
#pragma unroll
        for (int kb = 0; kb < 16; kb++) {
#pragma unroll
            for (int nt = 0; nt < 5; nt++) {
                f16x8 bf = *(const f16x8*)(bfl + ((size_t)((nt + 4) * 16 + kb) * 64 + lane) * 8);
                acc[nt] = __builtin_amdgcn_mfma_f32_32x32x16_f16(af[kb], bf, acc[nt], 0, 0, 0);
            }
        }
#pragma unroll
        for (int nt = 0; nt < 4; nt++)
#pragma unroll
            for (int r = 0; r < 16; r++) {
                int grow = r0 + (r & 3) + 8 * (r >> 2) + 4 * hi;
                if (grow < N0C) hs[(size_t)grow * 256 + 128 + nt * 32 + col] = (f16)acc[nt][r];
            }
#pragma unroll
        for (int r = 0; r < 16; r++) {
            int grow = r0 + (r & 3) + 8 * (r >> 2) + 4 * hi;
            float v = acc[4][r];
            if (col < 2) {
                if (grow < N0C) as_out[grow * 2 + col] = v;
            } else if (col < 4) {
                if (grow < N1C) ad_out[grow * 2 + (col - 2)] = v;
            }
        }
    }
}

// ---------------------------------------------------------------- gemm2 -----
// hs2 = h @ Ws2 -> [N1,128] f16, a_s2[N1], a_d2[N2] via pad tile.
__global__ __launch_bounds__(256, 2) void gemm2_kernel(
    const f16* __restrict__ h, const f16* __restrict__ bfl,
    f16* __restrict__ hs2, float* __restrict__ as_out, float* __restrict__ ad_out) {
    const int lane = threadIdx.x & 63, wave = threadIdx.x >> 6;
    const int col = lane & 31, hi = lane >> 5;
    const int r0 = blockIdx.x * 128 + wave * 32;
    const int row = r0 + col;

    f16x8 af[16];
#pragma unroll
    for (int kb = 0; kb < 16; kb++) {
        if (row < N1C)
            af[kb] = *(const f16x8*)(h + (size_t)row * 256 + kb * 16 + hi * 8);
        else
            af[kb] = (f16x8){0, 0, 0, 0, 0, 0, 0, 0};
    }

    f32x16 acc[5] = {};
#pragma unroll
    for (int kb = 0; kb < 16; kb++) {
#pragma unroll
        for (int nt = 0; nt < 5; nt++) {
            f16x8 bf = *(const f16x8*)(bfl + ((size_t)(nt * 16 + kb) * 64 + lane) * 8);
            acc[nt] = __builtin_amdgcn_mfma_f32_32x32x16_f16(af[kb], bf, acc[nt], 0, 0, 0);
        }
    }
#pragma unroll
    for (int nt = 0; nt < 4; nt++)
#pragma unroll
        for (int r = 0; r < 16; r++) {
            int grow = r0 + (r & 3) + 8 * (r >> 2) + 4 * hi;
            if (grow < N1C) hs2[(size_t)grow * 128 + nt * 32 + col] = (f16)acc[nt][r];
        }
#pragma unroll
    for (int r = 0; r < 16; r++) {
        int grow = r0 + (r & 3) + 8 * (r >> 2) + 4 * hi;
        float v = acc[4][r];
        if (col == 0) {
            if (grow < N1C) as_out[grow] = v;
        } else if (col == 1) {
            if (grow < N2C) ad_out[grow] = v;
        }
    }
}

// ---------------------------------------------------------------- agg1 ------
// one wave per dst node: masked edge softmax (heads=2) + gather-accumulate
// + fused bias/BN/leaky_relu(0.01), writes h [N1,256] f16
__global__ void agg1_kernel(const int* __restrict__ col1, const int* __restrict__ t1,
                            const int* __restrict__ timep, const int* __restrict__ intervalp,
                            const float* __restrict__ a_s, const float* __restrict__ a_d,
                            const f16* __restrict__ hs,
                            const float* __restrict__ bns, const float* __restrict__ bnt,
                            f16* __restrict__ h) {
    int wid = (blockIdx.x * blockDim.x + threadIdx.x) >> 6;
    if (wid >= N1C) return;
    int lane = threadIdx.x & 63;
    int T = timep[0], I = intervalp[0];
    int j = lane & 15;
    int c = col1[wid * 16 + j];
    int tv = t1[wid * 16 + j];
    bool mk = (tv >= T) && (tv < T + I);
    float e0 = -INFINITY, e1 = -INFINITY;
    if (mk) {
        float s0 = a_s[c * 2 + 0] + a_d[wid * 2 + 0];
        float s1 = a_s[c * 2 + 1] + a_d[wid * 2 + 1];
        e0 = s0 > 0.f ? s0 : 0.2f * s0;
        e1 = s1 > 0.f ? s1 : 0.2f * s1;
    }
    float m0 = e0, m1 = e1;
#pragma unroll
    for (int d = 1; d < 16; d <<= 1) {
        m0 = fmaxf(m0, __shfl_xor(m0, d));
        m1 = fmaxf(m1, __shfl_xor(m1, d));
    }
    float ex0 = mk ? __expf(e0 - m0) : 0.f;
    float ex1 = mk ? __expf(e1 - m1) : 0.f;
    float s0 = ex0, s1 = ex1;
#pragma unroll
    for (int d = 1; d < 16; d <<= 1) {
        s0 += __shfl_xor(s0, d);
        s1 += __shfl_xor(s1, d);
    }
    float r0 = 1.f / fmaxf(s0, 1e-16f);
    float r1 = 1.f / fmaxf(s1, 1e-16f);
    unsigned long long mb = __ballot(mk) & 0xFFFFull;
    int head = lane >> 5;
    float rden = head ? r1 : r0;
    float acc0 = 0.f, acc1 = 0.f, acc2 = 0.f, acc3 = 0.f;
    while (mb) {
        int jj = __builtin_ctzll(mb);
        mb &= mb - 1;
        int cj = __shfl(c, jj);
        float w0 = __shfl(ex0, jj), w1 = __shfl(ex1, jj);
        float w = (head ? w1 : w0) * rden;
        f16x4 v = *(const f16x4*)(hs + (size_t)cj * 256 + lane * 4);
        acc0 += w * (float)v[0];
        acc1 += w * (float)v[1];
        acc2 += w * (float)v[2];
        acc3 += w * (float)v[3];
    }
    int cb = lane * 4;
    float4 sc = *(const float4*)(bns + cb);
    float4 sh = *(const float4*)(bnt + cb);
    float o0 = acc0 * sc.x + sh.x; o0 = o0 > 0.f ? o0 : 0.01f * o0;
    float o1 = acc1 * sc.y + sh.y; o1 = o1 > 0.f ? o1 : 0.01f * o1;
    float o2 = acc2 * sc.z + sh.z; o2 = o2 > 0.f ? o2 : 0.01f * o2;
    float o3 = acc3 * sc.w + sh.w; o3 = o3 > 0.f ? o3 : 0.01f * o3;
    f16x4 ov = {(f16)o0, (f16)o1, (f16)o2, (f16)o3};
    *(f16x4*)(h + (size_t)wid * 256 + cb) = ov;
}

// ---------------------------------------------------------------- agg2 ------
// one wave per dst: masked softmax (1 head), gather [N1,128] f16, + b2, f32 out
__global__ void agg2_kernel(const int* __restrict__ col2, const int* __restrict__ t2,
                            const int* __restrict__ timep, const int* __restrict__ intervalp,
                            const float* __restrict__ a_s, const float* __restrict__ a_d,
                            const f16* __restrict__ hs2,
                            const float* __restrict__ b2, float* __restrict__ out) {
    int wid = (blockIdx.x * blockDim.x + threadIdx.x) >> 6;
    if (wid >= N2C) return;
    int lane = threadIdx.x & 63;
    int T = timep[0], I = intervalp[0];
    int j = lane & 15;
    int c = col2[wid * 16 + j];
    int tv = t2[wid * 16 + j];
    bool mk = (tv >= T) && (tv < T + I);
    float e = -INFINITY;
    if (mk) {
        float s = a_s[c] + a_d[wid];
        e = s > 0.f ? s : 0.2f * s;
    }
    float m = e;
#pragma unroll
    for (int d = 1; d < 16; d <<= 1) m = fmaxf(m, __shfl_xor(m, d));
    float ex = mk ? __expf(e - m) : 0.f;
    float s = ex;
#pragma unroll
    for (int d = 1; d < 16; d <<= 1) s += __shfl_xor(s, d);
    float r = 1.f / fmaxf(s, 1e-16f);
    unsigned long long mb = __ballot(mk) & 0xFFFFull;
    float acc0 = 0.f, acc1 = 0.f;
    while (mb) {
        int jj = __builtin_ctzll(mb);
        mb &= mb - 1;
        int cj = __shfl(c, jj);
        float w = __shfl(ex, jj) * r;
        f16x2 v = *(const f16x2*)(hs2 + (size_t)cj * 128 + lane * 2);
        acc0 += w * (float)v[0];
        acc1 += w * (float)v[1];
    }
    float2 o = make_float2(acc0 + b2[lane * 2], acc1 + b2[lane * 2 + 1]);
    *(float2*)(out + (size_t)wid * 128 + lane * 2) = o;
}

// ---------------------------------------------------------------- launch ----
extern "C" void kernel_launch(void* const* d_in, const int* in_sizes, int n_in,
                              void* d_out, int out_size, void* d_ws, size_t ws_size,
                              hipStream_t stream) {
    const float* x = (const float*)d_in[0];
    const int* col1 = (const int*)d_in[2];
    const int* t1 = (const int*)d_in[3];
    const int* col2 = (const int*)d_in[5];
    const int* t2 = (const int*)d_in[6];
    const int* timep = (const int*)d_in[7];
    const int* intervalp = (const int*)d_in[8];
    const float* Ws1 = (const float*)d_in[9];
    const float* Wd1 = (const float*)d_in[10];
    const float* as1 = (const float*)d_in[11];
    const float* ad1 = (const float*)d_in[12];
    const float* b1 = (const float*)d_in[13];
    const float* g1 = (const float*)d_in[14];
    const float* beta1 = (const float*)d_in[15];
    const float* m1 = (const float*)d_in[16];
    const float* v1 = (const float*)d_in[17];
    const float* Ws2 = (const float*)d_in[18];
    const float* Wd2 = (const float*)d_in[19];
    const float* as2 = (const float*)d_in[20];
    const float* ad2 = (const float*)d_in[21];
    const float* b2 = (const float*)d_in[22];
    float* out = (float*)d_out;

    char* ws = (char*)d_ws;
    size_t off = 0;
    auto alloc = [&](size_t bytes) {
        size_t o = off;
        off += (bytes + 511) & ~(size_t)511;
        return o;
    };
    f16* hs = (f16*)(ws + alloc((size_t)N0C * 256 * 2));
    f16* h = (f16*)(ws + alloc((size_t)N1C * 256 * 2));
    f16* hs2 = (f16*)(ws + alloc((size_t)N1C * 128 * 2));
    float* a_s1 = (float*)(ws + alloc((size_t)N0C * 2 * 4));
    float* a_d1 = (float*)(ws + alloc((size_t)N1C * 2 * 4));
    float* a_s2 = (float*)(ws + alloc((size_t)N1C * 4));
    float* a_d2 = (float*)(ws + alloc((size_t)N2C * 4));
    f16* bfl1 = (f16*)(ws + alloc((size_t)73728 * 2));
    f16* bfl2 = (f16*)(ws + alloc((size_t)40960 * 2));
    float* e1 = (float*)(ws + alloc(1024 * 4));
    float* e2 = (float*)(ws + alloc(512 * 4));
    float* bns = (float*)(ws + alloc(256 * 4));
    float* bnt = (float*)(ws + alloc(256 * 4));

    prep1_kernel<<<1, 256, 0, stream>>>(Ws1, Wd1, as1, ad1, Ws2, Wd2, as2, ad2,
                                        b1, g1, beta1, m1, v1, e1, e2, bns, bnt);
    prep2_kernel<<<448, 256, 0, stream>>>(Ws1, Ws2, e1, e2, bfl1, bfl2);
    gemm1_kernel<<<(N0C + 127) / 128, 256, 0, stream>>>(x, bfl1, hs, a_s1, a_d1);
    agg1_kernel<<<N1C / 4, 256, 0, stream>>>(col1, t1, timep, intervalp,
                                             a_s1, a_d1, hs, bns, bnt, h);
    gemm2_kernel<<<(N1C + 127) / 128, 256, 0, stream>>>(h, bfl2, hs2, a_s2, a_d2);
    agg2_kernel<<<N2C / 4, 256, 0, stream>>>(col2, t2, timep, intervalp,
                                             a_s2, a_d2, hs2, b2, out);
}

// Round 4
// 101.165 us; speedup vs baseline: 1.8400x; 1.5132x over previous
//
#include <hip/hip_runtime.h>
#include <hip/hip_bf16.h>

#define N0C 100000
#define N1C 50000
#define N2C 25000

typedef _Float16 f16;
typedef _Float16 f16x2 __attribute__((ext_vector_type(2)));
typedef _Float16 f16x4 __attribute__((ext_vector_type(4)));
typedef _Float16 f16x8 __attribute__((ext_vector_type(8)));
typedef float f32x16 __attribute__((ext_vector_type(16)));

typedef const __attribute__((address_space(1))) unsigned int guint;
typedef __attribute__((address_space(3))) unsigned int luint;
__device__ __forceinline__ void gload16(const void* g, void* l) {
    __builtin_amdgcn_global_load_lds((guint*)g, (luint*)l, 16, 0, 0);
}

// ---------------------------------------------------------------- prep1 -----
// e1[k][4] = {Ws1[:,0:128]@as1_h0, Ws1[:,128:]@as1_h1, Wd1[:,0:128]@ad1_h0, Wd1[:,128:]@ad1_h1}
// e2[k][2] = {Ws2@as2, Wd2@ad2};  bns/bnt = folded BN scale/shift
// one 64-lane block per k
__global__ void prep1_kernel(const float* __restrict__ Ws1, const float* __restrict__ Wd1,
                             const float* __restrict__ as1, const float* __restrict__ ad1,
                             const float* __restrict__ Ws2, const float* __restrict__ Wd2,
                             const float* __restrict__ as2, const float* __restrict__ ad2,
                             const float* __restrict__ b1, const float* __restrict__ g1,
                             const float* __restrict__ beta1, const float* __restrict__ m1,
                             const float* __restrict__ v1,
                             float* __restrict__ e1, float* __restrict__ e2,
                             float* __restrict__ bns, float* __restrict__ bnt) {
    int k = blockIdx.x, lane = threadIdx.x;
    float s0 = 0, s1 = 0, d0 = 0, d1 = 0, t0 = 0, t1 = 0;
    for (int c = lane; c < 128; c += 64) {
        s0 += Ws1[k * 256 + c] * as1[c];
        s1 += Ws1[k * 256 + 128 + c] * as1[128 + c];
        d0 += Wd1[k * 256 + c] * ad1[c];
        d1 += Wd1[k * 256 + 128 + c] * ad1[128 + c];
        t0 += Ws2[k * 128 + c] * as2[c];
        t1 += Wd2[k * 128 + c] * ad2[c];
    }
    for (int d = 1; d < 64; d <<= 1) {
        s0 += __shfl_xor(s0, d); s1 += __shfl_xor(s1, d);
        d0 += __shfl_xor(d0, d); d1 += __shfl_xor(d1, d);
        t0 += __shfl_xor(t0, d); t1 += __shfl_xor(t1, d);
    }
    if (lane == 0) {
        e1[k * 4 + 0] = s0; e1[k * 4 + 1] = s1; e1[k * 4 + 2] = d0; e1[k * 4 + 3] = d1;
        e2[k * 2 + 0] = t0; e2[k * 2 + 1] = t1;
        float sc = g1[k] * rsqrtf(v1[k] + 1e-5f);
        bns[k] = sc;
        bnt[k] = (b1[k] - m1[k]) * sc + beta1[k];
    }
}

// ---------------------------------------------------------------- prep2 -----
// fragment-linear B layouts for 32x32x16 MFMA:
// bfl1: [9 nt][16 kb][64 lane][8 j]  (nt 0-7: Ws1 cols; nt 8: e1 pad cols 0-3)
// bfl2: [5 nt][16 kb][64 lane][8 j]  (nt 0-3: Ws2 cols; nt 4: e2 pad cols 0-1)
// element (nt,kb,lane,j): n = nt*32 + (lane&31), k = kb*16 + (lane>>5)*8 + j
__global__ void prep2_kernel(const float* __restrict__ Ws1, const float* __restrict__ Ws2,
                             const float* __restrict__ e1, const float* __restrict__ e2,
                             f16* __restrict__ bfl1, f16* __restrict__ bfl2) {
    int i = blockIdx.x * 256 + threadIdx.x;
    if (i < 73728) {
        int j = i & 7, lane = (i >> 3) & 63, kb = (i >> 9) & 15, nt = i >> 13;
        int c = lane & 31, hi = lane >> 5;
        int k = kb * 16 + hi * 8 + j;
        float v;
        if (nt < 8) v = Ws1[k * 256 + nt * 32 + c];
        else v = (c < 4) ? e1[k * 4 + c] : 0.f;
        bfl1[i] = (f16)v;
    } else {
        int i2 = i - 73728;
        if (i2 < 40960) {
            int j = i2 & 7, lane = (i2 >> 3) & 63, kb = (i2 >> 9) & 15, nt = i2 >> 13;
            int c = lane & 31, hi = lane >> 5;
            int k = kb * 16 + hi * 8 + j;
            float v;
            if (nt < 4) v = Ws2[k * 128 + nt * 32 + c];
            else v = (c < 2) ? e2[k * 2 + c] : 0.f;
            bfl2[i2] = (f16)v;
        }
    }
}

// ---------------------------------------------------------------- gemm1 -----
// hs = f16(x) @ Ws1 -> [N0,256] f16, a_s1[N0][2], a_d1[N1][2] via pad tile (nt 8).
// Block: 128 rows x 288 cols, 8 waves = 4 row-tiles x 2 n-groups (nt 0-4 / 5-8).
// K-loop: 4 steps of BK=64. A: reg-stage f32->f16 -> XOR-swizzled LDS [128][64].
// B: global_load_lds width16 from fragment-linear bfl1 (linear LDS, conflict-free).
__global__ __launch_bounds__(512, 4) void gemm1_kernel(
    const float* __restrict__ x, const f16* __restrict__ bfl,
    f16* __restrict__ hs, float* __restrict__ as_out, float* __restrict__ ad_out) {
    __shared__ __align__(16) unsigned char smA[16384];
    __shared__ __align__(16) unsigned char smB[36864];
    const int t = threadIdx.x;
    const int wave = t >> 6, lane = t & 63;
    const int wr = wave & 3, wg = wave >> 2;
    const int col = lane & 31, hi = lane >> 5;
    const int r0 = blockIdx.x * 128;

    // A staging map: thread -> (row, quarter); 16 f32 per thread per step
    const int arow = t >> 2, aq = t & 3;
    const int agrow = r0 + arow;
    const int asw_st = (arow & 7) << 4;
    const bool aval = agrow < N0C;
    const float4* abase = (const float4*)(x + (size_t)agrow * 256);

    f32x16 acc[5] = {};

    for (int s = 0; s < 4; s++) {
        // issue B direct-to-LDS loads (fire-and-forget; drained by barrier)
        for (int c = wave; c < 36; c += 8) {
            int nt = c >> 2, kbl = c & 3;
            const f16* src = bfl + ((size_t)(nt * 16 + s * 4 + kbl) * 64 + lane) * 8;
            gload16(src, smB + c * 1024);
        }
        // A stage: 4x float4 load, cvt f16, 2x ds_write_b128 (swizzled)
        {
            float4 a0, a1, a2, a3;
            if (aval) {
                const float4* p = abase + s * 16 + aq * 4;
                a0 = p[0]; a1 = p[1]; a2 = p[2]; a3 = p[3];
            } else {
                a0 = make_float4(0.f, 0.f, 0.f, 0.f);
                a1 = a0; a2 = a0; a3 = a0;
            }
            f16x8 v0 = {(f16)a0.x, (f16)a0.y, (f16)a0.z, (f16)a0.w,
                        (f16)a1.x, (f16)a1.y, (f16)a1.z, (f16)a1.w};
            f16x8 v1 = {(f16)a2.x, (f16)a2.y, (f16)a2.z, (f16)a2.w,
                        (f16)a3.x, (f16)a3.y, (f16)a3.z, (f16)a3.w};
            unsigned char* wb = smA + arow * 128;
            *(f16x8*)(wb + ((aq * 32) ^ asw_st)) = v0;
            *(f16x8*)(wb + ((aq * 32 + 16) ^ asw_st)) = v1;
        }
        __syncthreads();
        const int myrow = wr * 32 + col;
        const int asw = (myrow & 7) << 4;
        const int abyte = myrow * 128 + hi * 16;
        if (wg == 0) {
#pragma unroll
            for (int kb = 0; kb < 4; kb++) {
                f16x8 af = *(const f16x8*)(smA + ((abyte + kb * 32) ^ asw));
#pragma unroll
                for (int j = 0; j < 5; j++) {
                    f16x8 bf = *(const f16x8*)(smB + (j * 4 + kb) * 1024 + lane * 16);
                    acc[j] = __builtin_amdgcn_mfma_f32_32x32x16_f16(af, bf, acc[j], 0, 0, 0);
                }
            }
        } else {
#pragma unroll
            for (int kb = 0; kb < 4; kb++) {
                f16x8 af = *(const f16x8*)(smA + ((abyte + kb * 32) ^ asw));
#pragma unroll
                for (int j = 0; j < 4; j++) {
                    f16x8 bf = *(const f16x8*)(smB + ((5 + j) * 4 + kb) * 1024 + lane * 16);
                    acc[j] = __builtin_amdgcn_mfma_f32_32x32x16_f16(af, bf, acc[j], 0, 0, 0);
                }
            }
        }
        __syncthreads();
    }

    // epilogue: C/D layout col=lane&31, row=(r&3)+8*(r>>2)+4*hi
    const int rbase = r0 + wr * 32 + 4 * hi;
    if (wg == 0) {
#pragma unroll
        for (int j = 0; j < 5; j++)
#pragma unroll
            for (int r = 0; r < 16; r++) {
                int grow = rbase + (r & 3) + 8 * (r >> 2);
                if (grow < N0C) hs[(size_t)grow * 256 + j * 32 + col] = (f16)acc[j][r];
            }
    } else {
#pragma unroll
        for (int j = 0; j < 3; j++)
#pragma unroll
            for (int r = 0; r < 16; r++) {
                int grow = rbase + (r & 3) + 8 * (r >> 2);
                if (grow < N0C) hs[(size_t)grow * 256 + (5 + j) * 32 + col] = (f16)acc[j][r];
            }
#pragma unroll
        for (int r = 0; r < 16; r++) {
            int grow = rbase + (r & 3) + 8 * (r >> 2);
            float v = acc[3][r];
            if (col < 2) {
                if (grow < N0C) as_out[grow * 2 + col] = v;
            } else if (col < 4) {
                if (grow < N1C) ad_out[grow * 2 + (col - 2)] = v;
            }
        }
    }
}

// ---------------------------------------------------------------- gemm2 -----
// hs2 = h @ Ws2 -> [N1,128] f16, a_s2[N1], a_d2[N2] via pad tile (nt 4).
// Same skeleton; A is f16 so it stages via global_load_lds with
// inverse-swizzled per-lane SOURCE (linear LDS dest), swizzled ds_read.
__global__ __launch_bounds__(512, 4) void gemm2_kernel(
    const f16* __restrict__ h, const f16* __restrict__ bfl,
    f16* __restrict__ hs2, float* __restrict__ as_out, float* __restrict__ ad_out) {
    __shared__ __align__(16) unsigned char smA[16384];
    __shared__ __align__(16) unsigned char smB[20480];
    const int t = threadIdx.x;
    const int wave = t >> 6, lane = t & 63;
    const int wr = wave & 3, wg = wave >> 2;
    const int col = lane & 31, hi = lane >> 5;
    const int r0 = blockIdx.x * 128;

    const int arow_l = lane >> 3;         // row within 8-row A chunk
    const int agr = (lane & 7) ^ arow_l;  // inverse-swizzled source granule

    f32x16 acc[3] = {};

    for (int s = 0; s < 4; s++) {
        for (int c = wave; c < 36; c += 8) {
            if (c < 16) {  // A chunks: rows c*8..c*8+7
                int rl = c * 8 + arow_l;
                int rsrc = r0 + rl;
                if (rsrc > N1C - 1) rsrc = N1C - 1;
                const f16* src = h + (size_t)rsrc * 256 + s * 64 + agr * 8;
                gload16(src, smA + c * 1024);
            } else {       // B chunks
                int c2 = c - 16;
                int nt = c2 >> 2, kbl = c2 & 3;
                const f16* src = bfl + ((size_t)(nt * 16 + s * 4 + kbl) * 64 + lane) * 8;
                gload16(src, smB + c2 * 1024);
            }
        }
        __syncthreads();
        const int myrow = wr * 32 + col;
        const int asw = (myrow & 7) << 4;
        const int abyte = myrow * 128 + hi * 16;
        if (wg == 0) {
#pragma unroll
            for (int kb = 0; kb < 4; kb++) {
                f16x8 af = *(const f16x8*)(smA + ((abyte + kb * 32) ^ asw));
#pragma unroll
                for (int j = 0; j < 3; j++) {
                    f16x8 bf = *(const f16x8*)(smB + (j * 4 + kb) * 1024 + lane * 16);
                    acc[j] = __builtin_amdgcn_mfma_f32_32x32x16_f16(af, bf, acc[j], 0, 0, 0);
                }
            }
        } else {
#pragma unroll
            for (int kb = 0; kb < 4; kb++) {
                f16x8 af = *(const f16x8*)(smA + ((abyte + kb * 32) ^ asw));
#pragma unroll
                for (int j = 0; j < 2; j++) {
                    f16x8 bf = *(const f16x8*)(smB + ((3 + j) * 4 + kb) * 1024 + lane * 16);
                    acc[j] = __builtin_amdgcn_mfma_f32_32x32x16_f16(af, bf, acc[j], 0, 0, 0);
                }
            }
        }
        __syncthreads();
    }

    const int rbase = r0 + wr * 32 + 4 * hi;
    if (wg == 0) {
#pragma unroll
        for (int j = 0; j < 3; j++)
#pragma unroll
            for (int r = 0; r < 16; r++) {
                int grow = rbase + (r & 3) + 8 * (r >> 2);
                if (grow < N1C) hs2[(size_t)grow * 128 + j * 32 + col] = (f16)acc[j][r];
            }
    } else {
#pragma unroll
        for (int r = 0; r < 16; r++) {
            int grow = rbase + (r & 3) + 8 * (r >> 2);
            if (grow < N1C) hs2[(size_t)grow * 128 + 3 * 32 + col] = (f16)acc[0][r];
        }
#pragma unroll
        for (int r = 0; r < 16; r++) {
            int grow = rbase + (r & 3) + 8 * (r >> 2);
            float v = acc[1][r];
            if (col == 0) {
                if (grow < N1C) as_out[grow] = v;
            } else if (col == 1) {
                if (grow < N2C) ad_out[grow] = v;
            }
        }
    }
}

// ---------------------------------------------------------------- agg1 ------
// one wave per dst node: masked edge softmax (heads=2) + gather-accumulate
// + fused bias/BN/leaky_relu(0.01), writes h [N1,256] f16
__global__ void agg1_kernel(const int* __restrict__ col1, const int* __restrict__ t1,
                            const int* __restrict__ timep, const int* __restrict__ intervalp,
                            const float* __restrict__ a_s, const float* __restrict__ a_d,
                            const f16* __restrict__ hs,
                            const float* __restrict__ bns, const float* __restrict__ bnt,
                            f16* __restrict__ h) {
    int wid = (blockIdx.x * blockDim.x + threadIdx.x) >> 6;
    if (wid >= N1C) return;
    int lane = threadIdx.x & 63;
    int T = timep[0], I = intervalp[0];
    int j = lane & 15;
    int c = col1[wid * 16 + j];
    int tv = t1[wid * 16 + j];
    bool mk = (tv >= T) && (tv < T + I);
    float e0 = -INFINITY, e1 = -INFINITY;
    if (mk) {
        float s0 = a_s[c * 2 + 0] + a_d[wid * 2 + 0];
        float s1 = a_s[c * 2 + 1] + a_d[wid * 2 + 1];
        e0 = s0 > 0.f ? s0 : 0.2f * s0;
        e1 = s1 > 0.f ? s1 : 0.2f * s1;
    }
    float m0 = e0, m1 = e1;
#pragma unroll
    for (int d = 1; d < 16; d <<= 1) {
        m0 = fmaxf(m0, __shfl_xor(m0, d));
        m1 = fmaxf(m1, __shfl_xor(m1, d));
    }
    float ex0 = mk ? __expf(e0 - m0) : 0.f;
    float ex1 = mk ? __expf(e1 - m1) : 0.f;
    float s0 = ex0, s1 = ex1;
#pragma unroll
    for (int d = 1; d < 16; d <<= 1) {
        s0 += __shfl_xor(s0, d);
        s1 += __shfl_xor(s1, d);
    }
    float r0 = 1.f / fmaxf(s0, 1e-16f);
    float r1 = 1.f / fmaxf(s1, 1e-16f);
    unsigned long long mb = __ballot(mk) & 0xFFFFull;
    int head = lane >> 5;
    float rden = head ? r1 : r0;
    float acc0 = 0.f, acc1 = 0.f, acc2 = 0.f, acc3 = 0.f;
    while (mb) {
        int jj = __builtin_ctzll(mb);
        mb &= mb - 1;
        int cj = __shfl(c, jj);
        float w0 = __shfl(ex0, jj), w1 = __shfl(ex1, jj);
        float w = (head ? w1 : w0) * rden;
        f16x4 v = *(const f16x4*)(hs + (size_t)cj * 256 + lane * 4);
        acc0 += w * (float)v[0];
        acc1 += w * (float)v[1];
        acc2 += w * (float)v[2];
        acc3 += w * (float)v[3];
    }
    int cb = lane * 4;
    float4 sc = *(const float4*)(bns + cb);
    float4 sh = *(const float4*)(bnt + cb);
    float o0 = acc0 * sc.x + sh.x; o0 = o0 > 0.f ? o0 : 0.01f * o0;
    float o1 = acc1 * sc.y + sh.y; o1 = o1 > 0.f ? o1 : 0.01f * o1;
    float o2 = acc2 * sc.z + sh.z; o2 = o2 > 0.f ? o2 : 0.01f * o2;
    float o3 = acc3 * sc.w + sh.w; o3 = o3 > 0.f ? o3 : 0.01f * o3;
    f16x4 ov = {(f16)o0, (f16)o1, (f16)o2, (f16)o3};
    *(f16x4*)(h + (size_t)wid * 256 + cb) = ov;
}

// ---------------------------------------------------------------- agg2 ------
// one wave per dst: masked softmax (1 head), gather [N1,128] f16, + b2, f32 out
__global__ void agg2_kernel(const int* __restrict__ col2, const int* __restrict__ t2,
                            const int* __restrict__ timep, const int* __restrict__ intervalp,
                            const float* __restrict__ a_s, const float* __restrict__ a_d,
                            const f16* __restrict__ hs2,
                            const float* __restrict__ b2, float* __restrict__ out) {
    int wid = (blockIdx.x * blockDim.x + threadIdx.x) >> 6;
    if (wid >= N2C) return;
    int lane = threadIdx.x & 63;
    int T = timep[0], I = intervalp[0];
    int j = lane & 15;
    int c = col2[wid * 16 + j];
    int tv = t2[wid * 16 + j];
    bool mk = (tv >= T) && (tv < T + I);
    float e = -INFINITY;
    if (mk) {
        float s = a_s[c] + a_d[wid];
        e = s > 0.f ? s : 0.2f * s;
    }
    float m = e;
#pragma unroll
    for (int d = 1; d < 16; d <<= 1) m = fmaxf(m, __shfl_xor(m, d));
    float ex = mk ? __expf(e - m) : 0.f;
    float s = ex;
#pragma unroll
    for (int d = 1; d < 16; d <<= 1) s += __shfl_xor(s, d);
    float r = 1.f / fmaxf(s, 1e-16f);
    unsigned long long mb = __ballot(mk) & 0xFFFFull;
    float acc0 = 0.f, acc1 = 0.f;
    while (mb) {
        int jj = __builtin_ctzll(mb);
        mb &= mb - 1;
        int cj = __shfl(c, jj);
        float w = __shfl(ex, jj) * r;
        f16x2 v = *(const f16x2*)(hs2 + (size_t)cj * 128 + lane * 2);
        acc0 += w * (float)v[0];
        acc1 += w * (float)v[1];
    }
    float2 o = make_float2(acc0 + b2[lane * 2], acc1 + b2[lane * 2 + 1]);
    *(float2*)(out + (size_t)wid * 128 + lane * 2) = o;
}

// ---------------------------------------------------------------- launch ----
extern "C" void kernel_launch(void* const* d_in, const int* in_sizes, int n_in,
                              void* d_out, int out_size, void* d_ws, size_t ws_size,
                              hipStream_t stream) {
    const float* x = (const float*)d_in[0];
    const int* col1 = (const int*)d_in[2];
    const int* t1 = (const int*)d_in[3];
    const int* col2 = (const int*)d_in[5];
    const int* t2 = (const int*)d_in[6];
    const int* timep = (const int*)d_in[7];
    const int* intervalp = (const int*)d_in[8];
    const float* Ws1 = (const float*)d_in[9];
    const float* Wd1 = (const float*)d_in[10];
    const float* as1 = (const float*)d_in[11];
    const float* ad1 = (const float*)d_in[12];
    const float* b1 = (const float*)d_in[13];
    const float* g1 = (const float*)d_in[14];
    const float* beta1 = (const float*)d_in[15];
    const float* m1 = (const float*)d_in[16];
    const float* v1 = (const float*)d_in[17];
    const float* Ws2 = (const float*)d_in[18];
    const float* Wd2 = (const float*)d_in[19];
    const float* as2 = (const float*)d_in[20];
    const float* ad2 = (const float*)d_in[21];
    const float* b2 = (const float*)d_in[22];
    float* out = (float*)d_out;

    char* ws = (char*)d_ws;
    size_t off = 0;
    auto alloc = [&](size_t bytes) {
        size_t o = off;
        off += (bytes + 511) & ~(size_t)511;
        return o;
    };
    f16* hs = (f16*)(ws + alloc((size_t)N0C * 256 * 2));
    f16* h = (f16*)(ws + alloc((size_t)N1C * 256 * 2));
    f16* hs2 = (f16*)(ws + alloc((size_t)N1C * 128 * 2));
    float* a_s1 = (float*)(ws + alloc((size_t)N0C * 2 * 4));
    float* a_d1 = (float*)(ws + alloc((size_t)N1C * 2 * 4));
    float* a_s2 = (float*)(ws + alloc((size_t)N1C * 4));
    float* a_d2 = (float*)(ws + alloc((size_t)N2C * 4));
    f16* bfl1 = (f16*)(ws + alloc((size_t)73728 * 2));
    f16* bfl2 = (f16*)(ws + alloc((size_t)40960 * 2));
    float* e1 = (float*)(ws + alloc(1024 * 4));
    float* e2 = (float*)(ws + alloc(512 * 4));
    float* bns = (float*)(ws + alloc(256 * 4));
    float* bnt = (float*)(ws + alloc(256 * 4));

    prep1_kernel<<<256, 64, 0, stream>>>(Ws1, Wd1, as1, ad1, Ws2, Wd2, as2, ad2,
                                         b1, g1, beta1, m1, v1, e1, e2, bns, bnt);
    prep2_kernel<<<448, 256, 0, stream>>>(Ws1, Ws2, e1, e2, bfl1, bfl2);
    gemm1_kernel<<<(N0C + 127) / 128, 512, 0, stream>>>(x, bfl1, hs, a_s1, a_d1);
    agg1_kernel<<<N1C / 4, 256, 0, stream>>>(col1, t1, timep, intervalp,
                                             a_s1, a_d1, hs, bns, bnt, h);
    gemm2_kernel<<<(N1C + 127) / 128, 512, 0, stream>>>(h, bfl2, hs2, a_s2, a_d2);
    agg2_kernel<<<N2C / 4, 256, 0, stream>>>(col2, t2, timep, intervalp,
                                             a_s2, a_d2, hs2, b2, out);
}